// Round 6
// baseline (197.090 us; speedup 1.0000x reference)
//
#include <hip/hip_runtime.h>

// Problem constants (from reference setup_inputs)
#define BB 8
#define CC 128
#define HH 128
#define WW 128
#define PLANE (HH * WW)      // 16384
#define KK 9                 // 3x3

// ---------------------------------------------------------------------------
// Kernel 1: pool + kerngen (last-finisher pattern, no grid sync, no spin).
// 1024 blocks x 512 threads, one (b,c) plane each.
//  - reduce plane -> agent-scope store psum[bc]; atomicAdd counter[b]
//  - the block seeing old==127 computes h[b] and kern[b][*] (1152 dots of 128)
// Deadlock-free: no block ever waits on another.
// ---------------------------------------------------------------------------
__global__ __launch_bounds__(512) void pool_kg_kernel(
        const float* __restrict__ x,
        const float* __restrict__ w1,
        const float* __restrict__ b1,
        const float* __restrict__ w2,
        const float* __restrict__ b2,
        float* __restrict__ psum,
        int* __restrict__ counter,
        float* __restrict__ kern) {
    int bc = blockIdx.x;
    int b = bc >> 7;
    int t = threadIdx.x;
    __shared__ float wsum[8];
    __shared__ int lastFlag;
    __shared__ float ps[CC];
    __shared__ float hs[CC];

    // ---- plane sum: 512 threads x 8 float4 ----
    const float4* g4 = (const float4*)(x + (size_t)bc * PLANE);
    float s = 0.f;
#pragma unroll
    for (int i = 0; i < 8; ++i) {
        float4 v = g4[t + i * 512];
        s += v.x + v.y + v.z + v.w;
    }
#pragma unroll
    for (int off = 32; off > 0; off >>= 1) s += __shfl_down(s, off, 64);
    int wave = t >> 6, lane = t & 63;
    if (lane == 0) wsum[wave] = s;
    if (t == 0) lastFlag = 0;
    __syncthreads();
    if (t == 0) {
        float tot = 0.f;
#pragma unroll
        for (int i = 0; i < 8; ++i) tot += wsum[i];
        __hip_atomic_store(&psum[bc], tot, __ATOMIC_RELEASE, __HIP_MEMORY_SCOPE_AGENT);
        int old = __hip_atomic_fetch_add(&counter[b], 1, __ATOMIC_ACQ_REL,
                                         __HIP_MEMORY_SCOPE_AGENT);
        if (old == CC - 1) lastFlag = 1;
    }
    __syncthreads();
    if (!lastFlag) return;

    // ---- last finisher for batch b: kerngen ----
    if (t < CC) {
        float v = __hip_atomic_load(&psum[b * CC + t], __ATOMIC_ACQUIRE,
                                    __HIP_MEMORY_SCOPE_AGENT);
        ps[t] = v * (1.0f / PLANE);
    }
    __syncthreads();

    // h[j] = relu(ps . w1[j] + b1[j]); 4 threads per j
    {
        int j = t >> 2, k = t & 3;
        const float* pr = ps + k * 32;
        const float* wr = w1 + j * CC + k * 32;
        float a = 0.f;
#pragma unroll
        for (int i = 0; i < 32; ++i) a += pr[i] * wr[i];
        a += __shfl_down(a, 1, 64);
        a += __shfl_down(a, 2, 64);
        if (k == 0) hs[j] = fmaxf(a + b1[j], 0.f);
    }
    __syncthreads();

    // kern[b][o] = hs . w2[o] + b2[o], o in [0,1152)
    const float4* hs4 = (const float4*)hs;
    for (int o = t; o < CC * KK; o += 512) {
        const float4* wr4 = (const float4*)(w2 + (size_t)o * CC);
        float a = 0.f;
#pragma unroll
        for (int i = 0; i < 32; ++i) {
            float4 wv = wr4[i];
            float4 hv = hs4[i];
            a += wv.x * hv.x + wv.y * hv.y + wv.z * hv.z + wv.w * hv.w;
        }
        kern[b * (CC * KK) + o] = a + b2[o];  // layout [b][c*9+p]
    }
}

// ---------------------------------------------------------------------------
// Kernel 2: dynamic depthwise 3x3 conv (cross-correlation, zero pad).
// 2048 blocks x 256 threads (8 blocks/CU). Each thread: sliding window over
// an 8-row x 4-col strip (10 row loads -> 1.25x redundancy, L3-resident).
// ---------------------------------------------------------------------------
__global__ __launch_bounds__(256) void conv_kernel(const float* __restrict__ x,
                                                   const float* __restrict__ kern,
                                                   float* __restrict__ out) {
    int bid = blockIdx.x;
    int bc = bid >> 1, half = bid & 1;
    const float* gplane = x + (size_t)bc * PLANE;
    float* oplane = out + (size_t)bc * PLANE;
    const float* wp = kern + (size_t)bc * KK;
    float w[9];
#pragma unroll
    for (int p = 0; p < 9; ++p) w[p] = wp[p];

    int t = threadIdx.x;
    int xq = t & 31;
    int x0 = xq << 2;
    int yb = half * 64 + (t >> 5) * 8;   // 8 row-groups of 8 rows per half

    float4 A  = {0.f, 0.f, 0.f, 0.f};  // partial for out row yr-1
    float4 Bv = {0.f, 0.f, 0.f, 0.f};  // partial for out row yr

#pragma unroll
    for (int si = 0; si < 10; ++si) {
        int yr = yb - 1 + si;
        float4 cv = {0.f, 0.f, 0.f, 0.f};
        float l = 0.f, r = 0.f;
        if (yr >= 0 && yr < HH) {
            const float* row = gplane + yr * WW;
            cv = *(const float4*)(row + x0);
            l = (xq > 0) ? row[x0 - 1] : 0.f;
            r = (xq < 31) ? row[x0 + 4] : 0.f;
        }
        // pbot completes out[yr-1]; pmid -> out[yr]; ptop -> out[yr+1]
        float4 pbot, pmid, ptop;
        pbot.x = w[6]*l    + w[7]*cv.x + w[8]*cv.y;
        pbot.y = w[6]*cv.x + w[7]*cv.y + w[8]*cv.z;
        pbot.z = w[6]*cv.y + w[7]*cv.z + w[8]*cv.w;
        pbot.w = w[6]*cv.z + w[7]*cv.w + w[8]*r;
        pmid.x = w[3]*l    + w[4]*cv.x + w[5]*cv.y;
        pmid.y = w[3]*cv.x + w[4]*cv.y + w[5]*cv.z;
        pmid.z = w[3]*cv.y + w[4]*cv.z + w[5]*cv.w;
        pmid.w = w[3]*cv.z + w[4]*cv.w + w[5]*r;
        ptop.x = w[0]*l    + w[1]*cv.x + w[2]*cv.y;
        ptop.y = w[0]*cv.x + w[1]*cv.y + w[2]*cv.z;
        ptop.z = w[0]*cv.y + w[1]*cv.z + w[2]*cv.w;
        ptop.w = w[0]*cv.z + w[1]*cv.w + w[2]*r;

        A.x += pbot.x; A.y += pbot.y; A.z += pbot.z; A.w += pbot.w;
        if (si >= 2) {   // yo = yr-1 in [yb, yb+8) exactly when si in [2,10)
            *(float4*)(oplane + (yr - 1) * WW + x0) = A;
        }
        Bv.x += pmid.x; Bv.y += pmid.y; Bv.z += pmid.z; Bv.w += pmid.w;
        A = Bv;
        Bv = ptop;
    }
}

// ---------------------------------------------------------------------------
extern "C" void kernel_launch(void* const* d_in, const int* in_sizes, int n_in,
                              void* d_out, int out_size, void* d_ws, size_t ws_size,
                              hipStream_t stream) {
    const float* x  = (const float*)d_in[0];
    const float* w1 = (const float*)d_in[1];
    const float* b1 = (const float*)d_in[2];
    const float* w2 = (const float*)d_in[3];
    const float* b2 = (const float*)d_in[4];
    float* out = (float*)d_out;

    int*   counter = (int*)d_ws;                 // 8 ints (batch counters)
    float* psum    = (float*)d_ws + 16;          // 1024 floats, 64B-aligned
    float* kern    = psum + BB * CC;             // 9216 floats

    hipMemsetAsync(counter, 0, BB * sizeof(int), stream);
    pool_kg_kernel<<<BB * CC, 512, 0, stream>>>(x, w1, b1, w2, b2,
                                                psum, counter, kern);
    conv_kernel<<<BB * CC * 2, 256, 0, stream>>>(x, kern, out);
}

// Round 7
// 146.481 us; speedup vs baseline: 1.3455x; 1.3455x over previous
//
#include <hip/hip_runtime.h>

// Problem constants (from reference setup_inputs)
#define BB 8
#define CC 128
#define HH 128
#define WW 128
#define PLANE (HH * WW)      // 16384
#define KK 9                 // 3x3

// ---------------------------------------------------------------------------
// Kernel 1: global average pool per (b,c) plane.
// 1024 blocks x 512 threads; each thread sums 8 float4s. ~11 us (HBM read BW).
// ---------------------------------------------------------------------------
__global__ __launch_bounds__(512) void pool_kernel(const float* __restrict__ x,
                                                   float* __restrict__ pooled) {
    int bc = blockIdx.x;
    const float4* p4 = (const float4*)(x + (size_t)bc * PLANE);
    int t = threadIdx.x;
    float s = 0.f;
#pragma unroll
    for (int i = 0; i < 8; ++i) {
        float4 v = p4[t + i * 512];
        s += v.x + v.y + v.z + v.w;
    }
#pragma unroll
    for (int off = 32; off > 0; off >>= 1) s += __shfl_down(s, off, 64);
    __shared__ float wsum[8];
    int wave = t >> 6, lane = t & 63;
    if (lane == 0) wsum[wave] = s;
    __syncthreads();
    if (t == 0) {
        float tot = 0.f;
#pragma unroll
        for (int i = 0; i < 8; ++i) tot += wsum[i];
        pooled[bc] = tot * (1.0f / PLANE);
    }
}

// ---------------------------------------------------------------------------
// Kernel 2: fused kerngen + depthwise 3x3 conv.
// 2048 blocks x 256 threads (8 blocks/CU), one half-plane (64 rows) each.
// Prologue (redundant per block): h[b] = relu(pooled@w1^T+b1) (w1 L2-hit),
// then this plane's 9 taps. Conv: 8-row sliding strips, float4 stores.
// ---------------------------------------------------------------------------
__global__ __launch_bounds__(256) void kgconv_kernel(
        const float* __restrict__ x,
        const float* __restrict__ pooled,
        const float* __restrict__ w1,
        const float* __restrict__ b1,
        const float* __restrict__ w2,
        const float* __restrict__ b2,
        float* __restrict__ out) {
    int bid = blockIdx.x;
    int bc = bid >> 1, half = bid & 1;
    int b = bc >> 7, c = bc & 127;
    int t = threadIdx.x;

    __shared__ float ps[CC];
    __shared__ float hs[CC];
    __shared__ float ks[KK];

    // ---- pooled row for batch b ----
    if (t < CC) ps[t] = pooled[b * CC + t];
    __syncthreads();

    // ---- h[j] = relu(ps . w1[j] + b1[j]); 2 threads per j ----
    {
        int j = t >> 1, k = t & 1;
        const float* pr = ps + k * 64;
        const float* wr = w1 + j * CC + k * 64;
        float a = 0.f;
#pragma unroll
        for (int i = 0; i < 64; ++i) a += pr[i] * wr[i];
        a += __shfl_down(a, 1, 64);          // pair (2j,2j+1) in-wave
        if (k == 0) hs[j] = fmaxf(a + b1[j], 0.f);
    }
    __syncthreads();

    // ---- ks[p] = hs . w2[c*9+p] + b2[c*9+p]; one wave per p ----
    {
        int wave = t >> 6, lane = t & 63;
        for (int p = wave; p < KK; p += 4) {
            int o = c * KK + p;
            const float* wr = w2 + (size_t)o * CC;
            float a = hs[lane] * wr[lane] + hs[lane + 64] * wr[lane + 64];
#pragma unroll
            for (int off = 32; off > 0; off >>= 1) a += __shfl_down(a, off, 64);
            if (lane == 0) ks[p] = a + b2[o];
        }
    }
    __syncthreads();

    float w[9];
#pragma unroll
    for (int p = 0; p < 9; ++p) w[p] = ks[p];

    // ---- conv: sliding window over an 8-row x 4-col strip ----
    const float* gplane = x + (size_t)bc * PLANE;
    float* oplane = out + (size_t)bc * PLANE;
    int xq = t & 31;
    int x0 = xq << 2;
    int yb = half * 64 + (t >> 5) * 8;   // 8 row-groups of 8 rows per half

    float4 A  = {0.f, 0.f, 0.f, 0.f};    // partial for out row yr-1
    float4 Bv = {0.f, 0.f, 0.f, 0.f};    // partial for out row yr

#pragma unroll
    for (int si = 0; si < 10; ++si) {
        int yr = yb - 1 + si;
        float4 cv = {0.f, 0.f, 0.f, 0.f};
        float l = 0.f, r = 0.f;
        if (yr >= 0 && yr < HH) {
            const float* row = gplane + yr * WW;
            cv = *(const float4*)(row + x0);
            l = (xq > 0) ? row[x0 - 1] : 0.f;
            r = (xq < 31) ? row[x0 + 4] : 0.f;
        }
        // pbot completes out[yr-1]; pmid -> out[yr]; ptop -> out[yr+1]
        float4 pbot, pmid, ptop;
        pbot.x = w[6]*l    + w[7]*cv.x + w[8]*cv.y;
        pbot.y = w[6]*cv.x + w[7]*cv.y + w[8]*cv.z;
        pbot.z = w[6]*cv.y + w[7]*cv.z + w[8]*cv.w;
        pbot.w = w[6]*cv.z + w[7]*cv.w + w[8]*r;
        pmid.x = w[3]*l    + w[4]*cv.x + w[5]*cv.y;
        pmid.y = w[3]*cv.x + w[4]*cv.y + w[5]*cv.z;
        pmid.z = w[3]*cv.y + w[4]*cv.z + w[5]*cv.w;
        pmid.w = w[3]*cv.z + w[4]*cv.w + w[5]*r;
        ptop.x = w[0]*l    + w[1]*cv.x + w[2]*cv.y;
        ptop.y = w[0]*cv.x + w[1]*cv.y + w[2]*cv.z;
        ptop.z = w[0]*cv.y + w[1]*cv.z + w[2]*cv.w;
        ptop.w = w[0]*cv.z + w[1]*cv.w + w[2]*r;

        A.x += pbot.x; A.y += pbot.y; A.z += pbot.z; A.w += pbot.w;
        if (si >= 2) {   // yo = yr-1 in [yb, yb+8) exactly when si in [2,10)
            *(float4*)(oplane + (yr - 1) * WW + x0) = A;
        }
        Bv.x += pmid.x; Bv.y += pmid.y; Bv.z += pmid.z; Bv.w += pmid.w;
        A = Bv;
        Bv = ptop;
    }
}

// ---------------------------------------------------------------------------
extern "C" void kernel_launch(void* const* d_in, const int* in_sizes, int n_in,
                              void* d_out, int out_size, void* d_ws, size_t ws_size,
                              hipStream_t stream) {
    const float* x  = (const float*)d_in[0];
    const float* w1 = (const float*)d_in[1];
    const float* b1 = (const float*)d_in[2];
    const float* w2 = (const float*)d_in[3];
    const float* b2 = (const float*)d_in[4];
    float* out = (float*)d_out;

    float* pooled = (float*)d_ws;   // B*C = 1024 floats

    pool_kernel<<<BB * CC, 512, 0, stream>>>(x, pooled);
    kgconv_kernel<<<BB * CC * 2, 256, 0, stream>>>(x, pooled, w1, b1, w2, b2, out);
}

// Round 8
// 134.514 us; speedup vs baseline: 1.4652x; 1.0890x over previous
//
#include <hip/hip_runtime.h>

// Problem constants (from reference setup_inputs)
#define BB 8
#define CC 128
#define HH 128
#define WW 128
#define PLANE (HH * WW)      // 16384
#define KK 9                 // 3x3

// ---------------------------------------------------------------------------
// Kernel 1: global average pool per (b,c) plane.
// 1024 blocks x 512 threads; each thread sums 8 float4s. ~11 us (HBM read BW).
// ---------------------------------------------------------------------------
__global__ __launch_bounds__(512) void pool_kernel(const float* __restrict__ x,
                                                   float* __restrict__ pooled) {
    int bc = blockIdx.x;
    const float4* p4 = (const float4*)(x + (size_t)bc * PLANE);
    int t = threadIdx.x;
    float s = 0.f;
#pragma unroll
    for (int i = 0; i < 8; ++i) {
        float4 v = p4[t + i * 512];
        s += v.x + v.y + v.z + v.w;
    }
#pragma unroll
    for (int off = 32; off > 0; off >>= 1) s += __shfl_down(s, off, 64);
    __shared__ float wsum[8];
    int wave = t >> 6, lane = t & 63;
    if (lane == 0) wsum[wave] = s;
    __syncthreads();
    if (t == 0) {
        float tot = 0.f;
#pragma unroll
        for (int i = 0; i < 8; ++i) tot += wsum[i];
        pooled[bc] = tot * (1.0f / PLANE);
    }
}

// ---------------------------------------------------------------------------
// Kernel 2: kernel generator (tiny, ~3 us).
// 72 blocks x 128 threads; each block redundantly computes h[b,:] in LDS,
// then 128 of the 1152 kern outputs for batch b.
// ---------------------------------------------------------------------------
__global__ __launch_bounds__(128) void kerngen_kernel(const float* __restrict__ pooled,
                                                      const float* __restrict__ w1,
                                                      const float* __restrict__ b1,
                                                      const float* __restrict__ w2,
                                                      const float* __restrict__ b2,
                                                      float* __restrict__ kern) {
    int b = blockIdx.x / 9;
    int g = blockIdx.x % 9;
    int j = threadIdx.x;
    __shared__ float ps[CC];
    __shared__ float hs[CC];
    ps[j] = pooled[b * CC + j];
    __syncthreads();
    float acc = b1[j];
    const float* w1r = w1 + j * CC;
#pragma unroll 8
    for (int i = 0; i < CC; ++i) acc += ps[i] * w1r[i];
    hs[j] = fmaxf(acc, 0.f);
    __syncthreads();
    int o = g * CC + j;              // [0, 1152)
    float acc2 = b2[o];
    const float* w2r = w2 + o * CC;
#pragma unroll 8
    for (int i = 0; i < CC; ++i) acc2 += hs[i] * w2r[i];
    kern[b * (CC * KK) + o] = acc2;  // layout [b][c*9+p]
}

// ---------------------------------------------------------------------------
// Kernel 3: dynamic depthwise 3x3 conv, MLP-maximized.
// 2048 blocks x 256 threads (8 blocks/CU), one half-plane each.
// Each thread: 8-row x 4-col strip. All 10 row loads hoisted into registers
// (10 loads in flight), halos via width-32 shuffles (no extra loads),
// 8 coalesced float4 stores.
// ---------------------------------------------------------------------------
__global__ __launch_bounds__(256) void conv_kernel(const float* __restrict__ x,
                                                   const float* __restrict__ kern,
                                                   float* __restrict__ out) {
    int bid = blockIdx.x;
    int bc = bid >> 1, half = bid & 1;
    const float* gplane = x + (size_t)bc * PLANE;
    float* oplane = out + (size_t)bc * PLANE;
    const float* wp = kern + (size_t)bc * KK;
    float w[9];
#pragma unroll
    for (int p = 0; p < 9; ++p) w[p] = wp[p];

    int t = threadIdx.x;
    int xq = t & 31;               // float4 column chunk within the row
    int x0 = xq << 2;
    int yb = half * 64 + (t >> 5) * 8;   // 8 row-groups of 8 rows per half

    // ---- hoisted loads: 10 input rows (yb-1 .. yb+8), all in flight ----
    float4 cv[10];
#pragma unroll
    for (int si = 0; si < 10; ++si) {
        int yr = yb - 1 + si;
        if (yr >= 0 && yr < HH)
            cv[si] = *(const float4*)(gplane + yr * WW + x0);
        else
            cv[si] = make_float4(0.f, 0.f, 0.f, 0.f);
    }

    // ---- halos via intra-row shuffles (width 32 isolates row-groups) ----
    float lv[10], rv[10];
#pragma unroll
    for (int si = 0; si < 10; ++si) {
        float lraw = __shfl_up(cv[si].w, 1, 32);
        float rraw = __shfl_down(cv[si].x, 1, 32);
        lv[si] = (xq == 0) ? 0.f : lraw;
        rv[si] = (xq == 31) ? 0.f : rraw;
    }

    // ---- 8 output rows; out[yb+o] uses input rows si = o, o+1, o+2 ----
#pragma unroll
    for (int o = 0; o < 8; ++o) {
        float4 acc = {0.f, 0.f, 0.f, 0.f};
#pragma unroll
        for (int ky = 0; ky < 3; ++ky) {
            int si = o + ky;
            float w0 = w[ky * 3], w1_ = w[ky * 3 + 1], w2_ = w[ky * 3 + 2];
            float4 c = cv[si];
            acc.x += w0 * lv[si] + w1_ * c.x + w2_ * c.y;
            acc.y += w0 * c.x   + w1_ * c.y + w2_ * c.z;
            acc.z += w0 * c.y   + w1_ * c.z + w2_ * c.w;
            acc.w += w0 * c.z   + w1_ * c.w + w2_ * rv[si];
        }
        *(float4*)(oplane + (yb + o) * WW + x0) = acc;
    }
}

// ---------------------------------------------------------------------------
extern "C" void kernel_launch(void* const* d_in, const int* in_sizes, int n_in,
                              void* d_out, int out_size, void* d_ws, size_t ws_size,
                              hipStream_t stream) {
    const float* x  = (const float*)d_in[0];
    const float* w1 = (const float*)d_in[1];
    const float* b1 = (const float*)d_in[2];
    const float* w2 = (const float*)d_in[3];
    const float* b2 = (const float*)d_in[4];
    float* out = (float*)d_out;

    float* ws = (float*)d_ws;
    float* pooled = ws;          // B*C = 1024 floats
    float* kern   = ws + 1024;   // B*C*9 = 9216 floats

    pool_kernel<<<BB * CC, 512, 0, stream>>>(x, pooled);
    kerngen_kernel<<<BB * 9, 128, 0, stream>>>(pooled, w1, b1, w2, b2, kern);
    conv_kernel<<<BB * CC * 2, 256, 0, stream>>>(x, kern, out);
}

// Round 9
// 134.208 us; speedup vs baseline: 1.4685x; 1.0023x over previous
//
#include <hip/hip_runtime.h>

// Problem constants (from reference setup_inputs)
#define BB 8
#define CC 128
#define HH 128
#define WW 128
#define PLANE (HH * WW)      // 16384
#define KK 9                 // 3x3

// ---------------------------------------------------------------------------
// Kernel 1: global average pool per (b,c) plane.
// 1024 blocks x 512 threads; each thread sums 8 float4s. ~11 us (HBM read BW).
// Normal (caching) loads on purpose: x must allocate in L3 for the conv pass.
// ---------------------------------------------------------------------------
__global__ __launch_bounds__(512) void pool_kernel(const float* __restrict__ x,
                                                   float* __restrict__ pooled) {
    int bc = blockIdx.x;
    const float4* p4 = (const float4*)(x + (size_t)bc * PLANE);
    int t = threadIdx.x;
    float s = 0.f;
#pragma unroll
    for (int i = 0; i < 8; ++i) {
        float4 v = p4[t + i * 512];
        s += v.x + v.y + v.z + v.w;
    }
#pragma unroll
    for (int off = 32; off > 0; off >>= 1) s += __shfl_down(s, off, 64);
    __shared__ float wsum[8];
    int wave = t >> 6, lane = t & 63;
    if (lane == 0) wsum[wave] = s;
    __syncthreads();
    if (t == 0) {
        float tot = 0.f;
#pragma unroll
        for (int i = 0; i < 8; ++i) tot += wsum[i];
        pooled[bc] = tot * (1.0f / PLANE);
    }
}

// ---------------------------------------------------------------------------
// Kernel 2: kernel generator (tiny, ~3 us).
// 72 blocks x 128 threads; each block redundantly computes h[b,:] in LDS,
// then 128 of the 1152 kern outputs for batch b.
// ---------------------------------------------------------------------------
__global__ __launch_bounds__(128) void kerngen_kernel(const float* __restrict__ pooled,
                                                      const float* __restrict__ w1,
                                                      const float* __restrict__ b1,
                                                      const float* __restrict__ w2,
                                                      const float* __restrict__ b2,
                                                      float* __restrict__ kern) {
    int b = blockIdx.x / 9;
    int g = blockIdx.x % 9;
    int j = threadIdx.x;
    __shared__ float ps[CC];
    __shared__ float hs[CC];
    ps[j] = pooled[b * CC + j];
    __syncthreads();
    float acc = b1[j];
    const float* w1r = w1 + j * CC;
#pragma unroll 8
    for (int i = 0; i < CC; ++i) acc += ps[i] * w1r[i];
    hs[j] = fmaxf(acc, 0.f);
    __syncthreads();
    int o = g * CC + j;              // [0, 1152)
    float acc2 = b2[o];
    const float* w2r = w2 + o * CC;
#pragma unroll 8
    for (int i = 0; i < CC; ++i) acc2 += hs[i] * w2r[i];
    kern[b * (CC * KK) + o] = acc2;  // layout [b][c*9+p]
}

// ---------------------------------------------------------------------------
// Kernel 3: dynamic depthwise 3x3 conv, MLP-maximized + non-temporal stores.
// 2048 blocks x 256 threads (8 blocks/CU), one half-plane each.
// Each thread: 8-row x 4-col strip. All 10 row loads hoisted (in flight),
// halos via width-32 shuffles, 8 coalesced float4 NT stores (out bypasses
// L2/L3 allocation so x stays L3-resident for the whole pass).
// ---------------------------------------------------------------------------
__global__ __launch_bounds__(256) void conv_kernel(const float* __restrict__ x,
                                                   const float* __restrict__ kern,
                                                   float* __restrict__ out) {
    int bid = blockIdx.x;
    int bc = bid >> 1, half = bid & 1;
    const float* gplane = x + (size_t)bc * PLANE;
    float* oplane = out + (size_t)bc * PLANE;
    const float* wp = kern + (size_t)bc * KK;
    float w[9];
#pragma unroll
    for (int p = 0; p < 9; ++p) w[p] = wp[p];

    int t = threadIdx.x;
    int xq = t & 31;               // float4 column chunk within the row
    int x0 = xq << 2;
    int yb = half * 64 + (t >> 5) * 8;   // 8 row-groups of 8 rows per half

    // ---- hoisted loads: 10 input rows (yb-1 .. yb+8), all in flight ----
    float4 cv[10];
#pragma unroll
    for (int si = 0; si < 10; ++si) {
        int yr = yb - 1 + si;
        if (yr >= 0 && yr < HH)
            cv[si] = *(const float4*)(gplane + yr * WW + x0);
        else
            cv[si] = make_float4(0.f, 0.f, 0.f, 0.f);
    }

    // ---- halos via intra-row shuffles (width 32 isolates row-groups) ----
    float lv[10], rv[10];
#pragma unroll
    for (int si = 0; si < 10; ++si) {
        float lraw = __shfl_up(cv[si].w, 1, 32);
        float rraw = __shfl_down(cv[si].x, 1, 32);
        lv[si] = (xq == 0) ? 0.f : lraw;
        rv[si] = (xq == 31) ? 0.f : rraw;
    }

    // ---- 8 output rows; out[yb+o] uses input rows si = o, o+1, o+2 ----
#pragma unroll
    for (int o = 0; o < 8; ++o) {
        float4 acc = {0.f, 0.f, 0.f, 0.f};
#pragma unroll
        for (int ky = 0; ky < 3; ++ky) {
            int si = o + ky;
            float w0 = w[ky * 3], w1_ = w[ky * 3 + 1], w2_ = w[ky * 3 + 2];
            float4 c = cv[si];
            acc.x += w0 * lv[si] + w1_ * c.x + w2_ * c.y;
            acc.y += w0 * c.x   + w1_ * c.y + w2_ * c.z;
            acc.z += w0 * c.y   + w1_ * c.z + w2_ * c.w;
            acc.w += w0 * c.z   + w1_ * c.w + w2_ * rv[si];
        }
        // non-temporal store: don't allocate out in L2/L3 (keep x resident)
        float* dst = oplane + (yb + o) * WW + x0;
        __builtin_nontemporal_store(acc.x, dst + 0);
        __builtin_nontemporal_store(acc.y, dst + 1);
        __builtin_nontemporal_store(acc.z, dst + 2);
        __builtin_nontemporal_store(acc.w, dst + 3);
    }
}

// ---------------------------------------------------------------------------
extern "C" void kernel_launch(void* const* d_in, const int* in_sizes, int n_in,
                              void* d_out, int out_size, void* d_ws, size_t ws_size,
                              hipStream_t stream) {
    const float* x  = (const float*)d_in[0];
    const float* w1 = (const float*)d_in[1];
    const float* b1 = (const float*)d_in[2];
    const float* w2 = (const float*)d_in[3];
    const float* b2 = (const float*)d_in[4];
    float* out = (float*)d_out;

    float* ws = (float*)d_ws;
    float* pooled = ws;          // B*C = 1024 floats
    float* kern   = ws + 1024;   // B*C*9 = 9216 floats

    pool_kernel<<<BB * CC, 512, 0, stream>>>(x, pooled);
    kerngen_kernel<<<BB * 9, 128, 0, stream>>>(pooled, w1, b1, w2, b2, kern);
    conv_kernel<<<BB * CC * 2, 256, 0, stream>>>(x, kern, out);
}